// Round 1
// baseline (23.508 us; speedup 1.0000x reference)
//
#include <hip/hip_runtime.h>

// Fused: LSTM cell (1 step, input=1, hidden=2) + ReLU + FC(2->128)+ReLU + FC(128->5)
// One thread per batch sample. All weights are wave-uniform -> scalar loads (SGPRs),
// so the inner loop is pure v_fma with SGPR operands.

#define FC1 128

__device__ __forceinline__ float sigmoid_f(float x) {
    return 1.0f / (1.0f + __expf(-x));
}
// tanh via 1 - 2/(e^{2x}+1): monotone, saturates to +/-1 without inf/inf NaN.
__device__ __forceinline__ float tanh_f(float x) {
    return 1.0f - 2.0f / (__expf(2.0f * x) + 1.0f);
}

__global__ __launch_bounds__(256) void lstm_mlp_kernel(
    const float* __restrict__ x,
    const float* __restrict__ h0,
    const float* __restrict__ c0,
    const float* __restrict__ W_ih,   // [8,1]
    const float* __restrict__ W_hh,   // [8,2]
    const float* __restrict__ b_ih,   // [8]
    const float* __restrict__ b_hh,   // [8]
    const float* __restrict__ W1,     // [128,2]
    const float* __restrict__ b1,     // [128]
    const float* __restrict__ W2,     // [5,128]
    const float* __restrict__ b2,     // [5]
    float* __restrict__ out,          // [B,5]
    int n)
{
    int i = blockIdx.x * blockDim.x + threadIdx.x;
    if (i >= n) return;

    float xv = x[i];
    float2 hp = reinterpret_cast<const float2*>(h0)[i];  // h_prev (zeros in setup, read anyway)
    float2 cp = reinterpret_cast<const float2*>(c0)[i];  // c_prev

    // gates[j] = W_ih[j]*x + W_hh[j][0]*h0 + W_hh[j][1]*h1 + b_ih[j] + b_hh[j]
    float gp[8];
#pragma unroll
    for (int j = 0; j < 8; ++j) {
        gp[j] = fmaf(W_ih[j], xv,
                 fmaf(W_hh[2*j], hp.x,
                  fmaf(W_hh[2*j+1], hp.y, b_ih[j] + b_hh[j])));
    }
    // PyTorch gate order: i, f, g, o (each of width HIDDEN=2)
    float i0 = sigmoid_f(gp[0]), i1 = sigmoid_f(gp[1]);
    float f0 = sigmoid_f(gp[2]), f1 = sigmoid_f(gp[3]);
    float g0 = tanh_f(gp[4]),    g1 = tanh_f(gp[5]);
    float o0 = sigmoid_f(gp[6]), o1 = sigmoid_f(gp[7]);

    float cn0 = fmaf(f0, cp.x, i0 * g0);
    float cn1 = fmaf(f1, cp.y, i1 * g1);
    float hn0 = o0 * tanh_f(cn0);
    float hn1 = o1 * tanh_f(cn1);
    float hx = fmaxf(hn0, 0.0f);   // relu(hn)
    float hy = fmaxf(hn1, 0.0f);

    // MLP head: u = relu(W1 @ h + b1); actions = W2 @ u + b2
    float a0 = b2[0], a1 = b2[1], a2 = b2[2], a3 = b2[3], a4 = b2[4];
#pragma unroll 16
    for (int j = 0; j < FC1; ++j) {
        float u = fmaf(W1[2*j], hx, fmaf(W1[2*j+1], hy, b1[j]));
        u = fmaxf(u, 0.0f);
        a0 = fmaf(W2[0*FC1 + j], u, a0);
        a1 = fmaf(W2[1*FC1 + j], u, a1);
        a2 = fmaf(W2[2*FC1 + j], u, a2);
        a3 = fmaf(W2[3*FC1 + j], u, a3);
        a4 = fmaf(W2[4*FC1 + j], u, a4);
    }

    float* op = out + (size_t)i * 5;
    op[0] = a0; op[1] = a1; op[2] = a2; op[3] = a3; op[4] = a4;
}

extern "C" void kernel_launch(void* const* d_in, const int* in_sizes, int n_in,
                              void* d_out, int out_size, void* d_ws, size_t ws_size,
                              hipStream_t stream) {
    const float* x    = (const float*)d_in[0];
    const float* h0   = (const float*)d_in[1];
    const float* c0   = (const float*)d_in[2];
    const float* W_ih = (const float*)d_in[3];
    const float* W_hh = (const float*)d_in[4];
    const float* b_ih = (const float*)d_in[5];
    const float* b_hh = (const float*)d_in[6];
    const float* W1   = (const float*)d_in[7];
    const float* b1   = (const float*)d_in[8];
    const float* W2   = (const float*)d_in[9];
    const float* b2   = (const float*)d_in[10];
    float* out = (float*)d_out;

    int n = in_sizes[0];  // B = 524288
    int block = 256;
    int grid = (n + block - 1) / block;
    lstm_mlp_kernel<<<grid, block, 0, stream>>>(
        x, h0, c0, W_ih, W_hh, b_ih, b_hh, W1, b1, W2, b2, out, n);
}

// Round 2
// 19.704 us; speedup vs baseline: 1.1931x; 1.1931x over previous
//
#include <hip/hip_runtime.h>

// Fused LSTM(1 step, in=1, hidden=2) + ReLU + FC(2->128)+ReLU + FC(128->5).
//
// Key structure: when h0 == 0 and c0 == 0 (the provided inputs), the output is
// a smooth function of the scalar x only: actions = F(x).  We tabulate F on a
// 4096-interval grid over [-8, 8] (lerp error ~1e-5 << 9.4e-3 threshold) in a
// small in-graph kernel, then the main kernel does a table lookup + lerp.
// Each thread still READS h,c and falls back to the exact full computation if
// any of them is nonzero -- correct for arbitrary inputs.

#define FC1 128
#define NT 4096              // intervals
#define XLO (-8.0f)
#define XHI (8.0f)

__device__ float g_lut[(NT + 1) * 8];   // [entry][0..4]=actions, 5..7 pad

__device__ __forceinline__ float sigmoid_f(float x) {
    return 1.0f / (1.0f + __expf(-x));
}
__device__ __forceinline__ float tanh_f(float x) {
    return 1.0f - 2.0f / (__expf(2.0f * x) + 1.0f);
}

// Exact model evaluation for one sample.
__device__ __forceinline__ void full_eval(
    float xv, float h0v, float h1v, float c0v, float c1v,
    const float* __restrict__ W_ih, const float* __restrict__ W_hh,
    const float* __restrict__ b_ih, const float* __restrict__ b_hh,
    const float* __restrict__ W1,   const float* __restrict__ b1,
    const float* __restrict__ W2,   const float* __restrict__ b2,
    float a[5])
{
    float gp[8];
#pragma unroll
    for (int j = 0; j < 8; ++j) {
        gp[j] = fmaf(W_ih[j], xv,
                 fmaf(W_hh[2*j], h0v,
                  fmaf(W_hh[2*j+1], h1v, b_ih[j] + b_hh[j])));
    }
    float i0 = sigmoid_f(gp[0]), i1 = sigmoid_f(gp[1]);
    float f0 = sigmoid_f(gp[2]), f1 = sigmoid_f(gp[3]);
    float g0 = tanh_f(gp[4]),    g1 = tanh_f(gp[5]);
    float o0 = sigmoid_f(gp[6]), o1 = sigmoid_f(gp[7]);

    float cn0 = fmaf(f0, c0v, i0 * g0);
    float cn1 = fmaf(f1, c1v, i1 * g1);
    float hx = fmaxf(o0 * tanh_f(cn0), 0.0f);
    float hy = fmaxf(o1 * tanh_f(cn1), 0.0f);

    float a0 = b2[0], a1 = b2[1], a2 = b2[2], a3 = b2[3], a4 = b2[4];
#pragma unroll 16
    for (int j = 0; j < FC1; ++j) {
        float u = fmaf(W1[2*j], hx, fmaf(W1[2*j+1], hy, b1[j]));
        u = fmaxf(u, 0.0f);
        a0 = fmaf(W2[0*FC1 + j], u, a0);
        a1 = fmaf(W2[1*FC1 + j], u, a1);
        a2 = fmaf(W2[2*FC1 + j], u, a2);
        a3 = fmaf(W2[3*FC1 + j], u, a3);
        a4 = fmaf(W2[4*FC1 + j], u, a4);
    }
    a[0] = a0; a[1] = a1; a[2] = a2; a[3] = a3; a[4] = a4;
}

__global__ __launch_bounds__(256) void build_lut_kernel(
    const float* __restrict__ W_ih, const float* __restrict__ W_hh,
    const float* __restrict__ b_ih, const float* __restrict__ b_hh,
    const float* __restrict__ W1,   const float* __restrict__ b1,
    const float* __restrict__ W2,   const float* __restrict__ b2)
{
    int t = blockIdx.x * blockDim.x + threadIdx.x;
    if (t > NT) return;
    float xv = XLO + (XHI - XLO) * ((float)t / (float)NT);
    float a[5];
    full_eval(xv, 0.0f, 0.0f, 0.0f, 0.0f,
              W_ih, W_hh, b_ih, b_hh, W1, b1, W2, b2, a);
    float* e = &g_lut[t * 8];
    e[0] = a[0]; e[1] = a[1]; e[2] = a[2]; e[3] = a[3]; e[4] = a[4];
    e[5] = 0.0f; e[6] = 0.0f; e[7] = 0.0f;
}

__global__ __launch_bounds__(256) void lstm_mlp_main(
    const float* __restrict__ x,
    const float* __restrict__ h0,
    const float* __restrict__ c0,
    const float* __restrict__ W_ih, const float* __restrict__ W_hh,
    const float* __restrict__ b_ih, const float* __restrict__ b_hh,
    const float* __restrict__ W1,   const float* __restrict__ b1,
    const float* __restrict__ W2,   const float* __restrict__ b2,
    float* __restrict__ out, int n)
{
    int i = blockIdx.x * blockDim.x + threadIdx.x;
    if (i >= n) return;

    float xv = x[i];
    float2 hp = reinterpret_cast<const float2*>(h0)[i];
    float2 cp = reinterpret_cast<const float2*>(c0)[i];

    float a[5];
    if (hp.x == 0.0f && hp.y == 0.0f && cp.x == 0.0f && cp.y == 0.0f) {
        // LUT path: actions = lerp(F) at x
        float t = (xv - XLO) * ((float)NT / (XHI - XLO));
        t = fminf(fmaxf(t, 0.0f), (float)NT);
        int k = min((int)t, NT - 1);
        float frac = t - (float)k;
        const float4* plo = reinterpret_cast<const float4*>(&g_lut[k * 8]);
        const float4* phi = reinterpret_cast<const float4*>(&g_lut[(k + 1) * 8]);
        float4 lo = plo[0];
        float  lo4 = g_lut[k * 8 + 4];
        float4 hi = phi[0];
        float  hi4 = g_lut[(k + 1) * 8 + 4];
        a[0] = fmaf(frac, hi.x - lo.x, lo.x);
        a[1] = fmaf(frac, hi.y - lo.y, lo.y);
        a[2] = fmaf(frac, hi.z - lo.z, lo.z);
        a[3] = fmaf(frac, hi.w - lo.w, lo.w);
        a[4] = fmaf(frac, hi4 - lo4, lo4);
    } else {
        // exact path for arbitrary h,c
        full_eval(xv, hp.x, hp.y, cp.x, cp.y,
                  W_ih, W_hh, b_ih, b_hh, W1, b1, W2, b2, a);
    }

    float* op = out + (size_t)i * 5;
    op[0] = a[0]; op[1] = a[1]; op[2] = a[2]; op[3] = a[3]; op[4] = a[4];
}

extern "C" void kernel_launch(void* const* d_in, const int* in_sizes, int n_in,
                              void* d_out, int out_size, void* d_ws, size_t ws_size,
                              hipStream_t stream) {
    const float* x    = (const float*)d_in[0];
    const float* h0   = (const float*)d_in[1];
    const float* c0   = (const float*)d_in[2];
    const float* W_ih = (const float*)d_in[3];
    const float* W_hh = (const float*)d_in[4];
    const float* b_ih = (const float*)d_in[5];
    const float* b_hh = (const float*)d_in[6];
    const float* W1   = (const float*)d_in[7];
    const float* b1   = (const float*)d_in[8];
    const float* W2   = (const float*)d_in[9];
    const float* b2   = (const float*)d_in[10];
    float* out = (float*)d_out;

    int n = in_sizes[0];  // B = 524288

    // 1) build the F(x) table (NT+1 = 4097 entries)
    build_lut_kernel<<<(NT + 1 + 255) / 256, 256, 0, stream>>>(
        W_ih, W_hh, b_ih, b_hh, W1, b1, W2, b2);

    // 2) main pass
    int block = 256;
    int grid = (n + block - 1) / block;
    lstm_mlp_main<<<grid, block, 0, stream>>>(
        x, h0, c0, W_ih, W_hh, b_ih, b_hh, W1, b1, W2, b2, out, n);
}

// Round 3
// 16.830 us; speedup vs baseline: 1.3968x; 1.1708x over previous
//
#include <hip/hip_runtime.h>

// Fused LSTM(1 step, in=1, hidden=2) + ReLU + FC(2->128)+ReLU + FC(128->5).
//
// Structure: when h0==0 && c0==0 (the provided inputs) and XLO<x<XHI, the
// output is a smooth scalar function F(x); we tabulate F on a 4096-interval
// grid (lerp error ~1e-5 << 9.4e-3 threshold) with a parallel in-graph build
// kernel (8 lanes per entry, shfl reduce), then the main kernel does a
// lookup+lerp at 2 samples/thread. Any thread whose h/c is nonzero or x out
// of range takes the exact full-compute path -- correct for arbitrary inputs.

#define FC1 128
#define NT 4096              // intervals
#define XLO (-8.0f)
#define XHI (8.0f)

__device__ float g_lut[(NT + 1) * 8];   // [entry][0..3]=a0..a3, [4]=a4, 5..7 pad

__device__ __forceinline__ float sigmoid_f(float x) {
    return 1.0f / (1.0f + __expf(-x));
}
__device__ __forceinline__ float tanh_f(float x) {
    return 1.0f - 2.0f / (__expf(2.0f * x) + 1.0f);
}

// LSTM cell -> relu(h) for one sample.
__device__ __forceinline__ void lstm_part(
    float xv, float h0v, float h1v, float c0v, float c1v,
    const float* __restrict__ W_ih, const float* __restrict__ W_hh,
    const float* __restrict__ b_ih, const float* __restrict__ b_hh,
    float& hx, float& hy)
{
    float gp[8];
#pragma unroll
    for (int j = 0; j < 8; ++j) {
        gp[j] = fmaf(W_ih[j], xv,
                 fmaf(W_hh[2*j], h0v,
                  fmaf(W_hh[2*j+1], h1v, b_ih[j] + b_hh[j])));
    }
    float i0 = sigmoid_f(gp[0]), i1 = sigmoid_f(gp[1]);
    float f0 = sigmoid_f(gp[2]), f1 = sigmoid_f(gp[3]);
    float g0 = tanh_f(gp[4]),    g1 = tanh_f(gp[5]);
    float o0 = sigmoid_f(gp[6]), o1 = sigmoid_f(gp[7]);
    float cn0 = fmaf(f0, c0v, i0 * g0);
    float cn1 = fmaf(f1, c1v, i1 * g1);
    hx = fmaxf(o0 * tanh_f(cn0), 0.0f);
    hy = fmaxf(o1 * tanh_f(cn1), 0.0f);
}

// Exact model evaluation for one sample (fallback path).
__device__ __forceinline__ void full_eval(
    float xv, float h0v, float h1v, float c0v, float c1v,
    const float* __restrict__ W_ih, const float* __restrict__ W_hh,
    const float* __restrict__ b_ih, const float* __restrict__ b_hh,
    const float* __restrict__ W1,   const float* __restrict__ b1,
    const float* __restrict__ W2,   const float* __restrict__ b2,
    float a[5])
{
    float hx, hy;
    lstm_part(xv, h0v, h1v, c0v, c1v, W_ih, W_hh, b_ih, b_hh, hx, hy);
    float a0 = b2[0], a1 = b2[1], a2 = b2[2], a3 = b2[3], a4 = b2[4];
#pragma unroll 16
    for (int j = 0; j < FC1; ++j) {
        float u = fmaf(W1[2*j], hx, fmaf(W1[2*j+1], hy, b1[j]));
        u = fmaxf(u, 0.0f);
        a0 = fmaf(W2[0*FC1 + j], u, a0);
        a1 = fmaf(W2[1*FC1 + j], u, a1);
        a2 = fmaf(W2[2*FC1 + j], u, a2);
        a3 = fmaf(W2[3*FC1 + j], u, a3);
        a4 = fmaf(W2[4*FC1 + j], u, a4);
    }
    a[0] = a0; a[1] = a1; a[2] = a2; a[3] = a3; a[4] = a4;
}

// LUT build: 8 lanes per table entry; lane l handles FC1 neurons
// [16l, 16l+16), then shfl-xor reduce within the 8-lane group.
__global__ __launch_bounds__(256) void build_lut_kernel(
    const float* __restrict__ W_ih, const float* __restrict__ W_hh,
    const float* __restrict__ b_ih, const float* __restrict__ b_hh,
    const float* __restrict__ W1,   const float* __restrict__ b1,
    const float* __restrict__ W2,   const float* __restrict__ b2)
{
    int tid = blockIdx.x * blockDim.x + threadIdx.x;
    int e = tid >> 3;
    int l = tid & 7;
    if (e > NT) return;

    float xv = XLO + (XHI - XLO) * ((float)e / (float)NT);
    float hx, hy;
    lstm_part(xv, 0.0f, 0.0f, 0.0f, 0.0f, W_ih, W_hh, b_ih, b_hh, hx, hy);

    float a0 = 0.f, a1 = 0.f, a2 = 0.f, a3 = 0.f, a4 = 0.f;
    int j0 = l * 16;
#pragma unroll
    for (int jj = 0; jj < 16; ++jj) {
        int j = j0 + jj;
        float u = fmaf(W1[2*j], hx, fmaf(W1[2*j+1], hy, b1[j]));
        u = fmaxf(u, 0.0f);
        a0 = fmaf(W2[0*FC1 + j], u, a0);
        a1 = fmaf(W2[1*FC1 + j], u, a1);
        a2 = fmaf(W2[2*FC1 + j], u, a2);
        a3 = fmaf(W2[3*FC1 + j], u, a3);
        a4 = fmaf(W2[4*FC1 + j], u, a4);
    }
#pragma unroll
    for (int m = 1; m < 8; m <<= 1) {
        a0 += __shfl_xor(a0, m);
        a1 += __shfl_xor(a1, m);
        a2 += __shfl_xor(a2, m);
        a3 += __shfl_xor(a3, m);
        a4 += __shfl_xor(a4, m);
    }
    if (l == 0) {
        float4* ep = reinterpret_cast<float4*>(&g_lut[e * 8]);
        ep[0] = make_float4(a0 + b2[0], a1 + b2[1], a2 + b2[2], a3 + b2[3]);
        ep[1] = make_float4(a4 + b2[4], 0.f, 0.f, 0.f);
    }
}

__device__ __forceinline__ void eval_sample(
    float xv, float h0v, float h1v, float c0v, float c1v,
    const float* __restrict__ W_ih, const float* __restrict__ W_hh,
    const float* __restrict__ b_ih, const float* __restrict__ b_hh,
    const float* __restrict__ W1,   const float* __restrict__ b1,
    const float* __restrict__ W2,   const float* __restrict__ b2,
    float a[5])
{
    if (h0v == 0.0f && h1v == 0.0f && c0v == 0.0f && c1v == 0.0f &&
        xv > XLO && xv < XHI) {
        float t = (xv - XLO) * ((float)NT / (XHI - XLO));
        int k = min((int)t, NT - 1);
        float frac = t - (float)k;
        const float* e = &g_lut[k * 8];
        float4 lo = *reinterpret_cast<const float4*>(e);
        float  lo4 = e[4];
        float4 hi = *reinterpret_cast<const float4*>(e + 8);
        float  hi4 = e[12];
        a[0] = fmaf(frac, hi.x - lo.x, lo.x);
        a[1] = fmaf(frac, hi.y - lo.y, lo.y);
        a[2] = fmaf(frac, hi.z - lo.z, lo.z);
        a[3] = fmaf(frac, hi.w - lo.w, lo.w);
        a[4] = fmaf(frac, hi4 - lo4, lo4);
    } else {
        full_eval(xv, h0v, h1v, c0v, c1v,
                  W_ih, W_hh, b_ih, b_hh, W1, b1, W2, b2, a);
    }
}

// 2 samples per thread.
__global__ __launch_bounds__(256) void lstm_mlp_main(
    const float* __restrict__ x,
    const float* __restrict__ h0,
    const float* __restrict__ c0,
    const float* __restrict__ W_ih, const float* __restrict__ W_hh,
    const float* __restrict__ b_ih, const float* __restrict__ b_hh,
    const float* __restrict__ W1,   const float* __restrict__ b1,
    const float* __restrict__ W2,   const float* __restrict__ b2,
    float* __restrict__ out, int n)
{
    int t = blockIdx.x * blockDim.x + threadIdx.x;
    int i = t * 2;
    if (i >= n) return;

    float2 xv = *reinterpret_cast<const float2*>(x + i);
    float4 hp = *reinterpret_cast<const float4*>(h0 + 2 * (size_t)i);
    float4 cp = *reinterpret_cast<const float4*>(c0 + 2 * (size_t)i);

    float r[10];
    eval_sample(xv.x, hp.x, hp.y, cp.x, cp.y,
                W_ih, W_hh, b_ih, b_hh, W1, b1, W2, b2, r);
    eval_sample(xv.y, hp.z, hp.w, cp.z, cp.w,
                W_ih, W_hh, b_ih, b_hh, W1, b1, W2, b2, r + 5);

    float2* op = reinterpret_cast<float2*>(out + (size_t)i * 5);
    op[0] = make_float2(r[0], r[1]);
    op[1] = make_float2(r[2], r[3]);
    op[2] = make_float2(r[4], r[5]);
    op[3] = make_float2(r[6], r[7]);
    op[4] = make_float2(r[8], r[9]);
}

extern "C" void kernel_launch(void* const* d_in, const int* in_sizes, int n_in,
                              void* d_out, int out_size, void* d_ws, size_t ws_size,
                              hipStream_t stream) {
    const float* x    = (const float*)d_in[0];
    const float* h0   = (const float*)d_in[1];
    const float* c0   = (const float*)d_in[2];
    const float* W_ih = (const float*)d_in[3];
    const float* W_hh = (const float*)d_in[4];
    const float* b_ih = (const float*)d_in[5];
    const float* b_hh = (const float*)d_in[6];
    const float* W1   = (const float*)d_in[7];
    const float* b1   = (const float*)d_in[8];
    const float* W2   = (const float*)d_in[9];
    const float* b2   = (const float*)d_in[10];
    float* out = (float*)d_out;

    int n = in_sizes[0];  // B = 524288 (even)

    // 1) build the F(x) table: (NT+1)*8 threads
    int bt = (NT + 1) * 8;
    build_lut_kernel<<<(bt + 255) / 256, 256, 0, stream>>>(
        W_ih, W_hh, b_ih, b_hh, W1, b1, W2, b2);

    // 2) main pass: 2 samples/thread
    int threads = n / 2;
    int block = 256;
    int grid = (threads + block - 1) / block;
    lstm_mlp_main<<<grid, block, 0, stream>>>(
        x, h0, c0, W_ih, W_hh, b_ih, b_hh, W1, b1, W2, b2, out, n);
}